// Round 7
// baseline (610.040 us; speedup 1.0000x reference)
//
#include <hip/hip_runtime.h>

#define NN 100000
#define NNP 100032          // padded to 64-node tiles
#define NE 1200000
#define DIN 7
#define DD 64
#define NL 3
#define NG 64
#define PCH 16
#define NCHUNK (NN / PCH)   // 6250
#define RB 782              // row/col buckets: 99999>>7 = 781
#define BCAP 2048           // per-bucket capacity (mean 1535, std ~39)
#define B1 250              // pass-1 blocks (1024 threads each)
#define CHUNK (NE / B1)     // 4800 exact

typedef float f32x4 __attribute__((ext_vector_type(4)));

__device__ inline f32x4 relu4(f32x4 v) {
    v[0] = fmaxf(v[0], 0.f); v[1] = fmaxf(v[1], 0.f);
    v[2] = fmaxf(v[2], 0.f); v[3] = fmaxf(v[3], 0.f);
    return v;
}
__device__ inline unsigned short f2bf(float f) {        // RNE bf16
    unsigned u = __float_as_uint(f);
    return (unsigned short)((u + 0x7fffu + ((u >> 16) & 1u)) >> 16);
}
__device__ inline float bf2f(unsigned short h) {
    return __uint_as_float(((unsigned)h) << 16);
}

// ------------- fused embed: A = relu(x@Wn) fp32; YAbf[n] = [y bf16 (64) | A bf16 (64)] -------------
__global__ __launch_bounds__(256) void k_embed_xy(const float* __restrict__ x,
        const float* __restrict__ Wn, const float* __restrict__ Wne,
        float* __restrict__ A, unsigned short* __restrict__ yab,
        float* __restrict__ yf) {
    __shared__ float sWn[DIN * DD];
    __shared__ float sWy[DIN * DD];
    int t = threadIdx.x;
    for (int i = t; i < DIN * DD; i += 256) {
        sWn[i] = Wn[i];
        int k = i >> 6, d = i & 63;
        sWy[i] = (d < 63) ? Wne[(k + 1) * 63 + d] : 0.f;
    }
    __syncthreads();
    int gid = blockIdx.x * 256 + t;          // exact grid: NN*DD/256
    int n = gid >> 6, d = gid & 63;
    const float* xr = x + n * DIN;
    float a = 0.f, y = 0.f;
#pragma unroll
    for (int k = 0; k < DIN; ++k) {
        float xv = xr[k];
        a = fmaf(xv, sWn[k * DD + d], a);
        y = fmaf(xv, sWy[k * DD + d], y);
    }
    float ar = fmaxf(a, 0.f);
    A[gid] = ar;
    if (yab) {
        yab[(size_t)n * 128 + d] = f2bf(y);
        yab[(size_t)n * 128 + 64 + d] = f2bf(ar);
    }
    if (yf) yf[gid] = y;
}

// ---------------- CSR build via LDS bucket sort ----------------
__global__ __launch_bounds__(1024) void k_bucket(const int* __restrict__ ei,
        const float* __restrict__ ea, int* __restrict__ gR, int* __restrict__ gC,
        uint4* __restrict__ tmpR, int* __restrict__ tmpC) {
    __shared__ int hR[RB], hC[RB];
    int t = threadIdx.x;
    for (int i = t; i < RB; i += 1024) { hR[i] = 0; hC[i] = 0; }
    __syncthreads();
    int e0 = blockIdx.x * CHUNK, e1 = e0 + CHUNK;
    for (int e = e0 + t; e < e1; e += 1024) {
        atomicAdd(&hR[ei[e] >> 7], 1);
        atomicAdd(&hC[ei[NE + e] >> 7], 1);
    }
    __syncthreads();
    for (int b = t; b < RB; b += 1024) {
        int n = hR[b]; hR[b] = n ? atomicAdd(&gR[b], n) : 0;
        n = hC[b];     hC[b] = n ? atomicAdd(&gC[b], n) : 0;
    }
    __syncthreads();
    for (int e = e0 + t; e < e1; e += 1024) {
        int r = ei[e], c = ei[NE + e];
        float a = ea[e];
        int br = r >> 7, bc = c >> 7;
        int ir = atomicAdd(&hR[br], 1);
        if (ir < BCAP) tmpR[(size_t)br * BCAP + ir] = make_uint4((unsigned)r, (unsigned)c, __float_as_uint(a), 0u);
        int ic = atomicAdd(&hC[bc], 1);
        if (ic < BCAP) tmpC[(size_t)bc * BCAP + ic] = c;
    }
}

__global__ __launch_bounds__(1024) void k_bscan(const int* __restrict__ gR,
        int* __restrict__ bsR) {
    __shared__ int s[1024];
    int t = threadIdx.x;
    int v = (t < RB) ? gR[t] : 0;
    s[t] = v; __syncthreads();
    for (int off = 1; off < 1024; off <<= 1) {
        int u = (t >= off) ? s[t - off] : 0; __syncthreads();
        s[t] += u; __syncthreads();
    }
    if (t < RB) bsR[t] = s[t] - v;
}

__global__ __launch_bounds__(256) void k_sortbucket(const int* __restrict__ gR,
        const int* __restrict__ bsR, const uint4* __restrict__ tmpR,
        int* __restrict__ rowptr, int* __restrict__ ecol, float* __restrict__ eat) {
    __shared__ uint4 sbuf[BCAP];              // 32 KB
    __shared__ int cnt128[128], off128[128], sscan[128];
    int b = blockIdx.x, t = threadIdx.x;
    int cnt = min(gR[b], BCAP);
    int base = bsR[b];
    if (t < 128) cnt128[t] = 0;
    __syncthreads();
    for (int i = t; i < cnt; i += 256) {
        uint4 rec = tmpR[(size_t)b * BCAP + i];
        sbuf[i] = rec;
        atomicAdd(&cnt128[rec.x & 127], 1);
    }
    __syncthreads();
    if (t < 128) sscan[t] = cnt128[t];
    __syncthreads();
    for (int off = 1; off < 128; off <<= 1) {
        int u = (t < 128 && t >= off) ? sscan[t - off] : 0;
        __syncthreads();
        if (t < 128) sscan[t] += u;
        __syncthreads();
    }
    if (t < 128) {
        int excl = sscan[t] - cnt128[t];
        off128[t] = excl;
        int row = (b << 7) + t;
        if (row <= NN) rowptr[row] = base + excl;
    }
    __syncthreads();
    for (int i = t; i < cnt; i += 256) {
        uint4 rec = sbuf[i];
        int p = atomicAdd(&off128[rec.x & 127], 1);
        ecol[base + p] = (int)rec.y;
        eat[base + p] = __uint_as_float(rec.z);
    }
}

__global__ __launch_bounds__(256) void k_degbucket(const int* __restrict__ gC,
        const int* __restrict__ tmpC, int* __restrict__ degi) {
    __shared__ int cnt128[128];
    int b = blockIdx.x, t = threadIdx.x;
    int cnt = min(gC[b], BCAP);
    if (t < 128) cnt128[t] = 0;
    __syncthreads();
    for (int i = t; i < cnt; i += 256)
        atomicAdd(&cnt128[tmpC[(size_t)b * BCAP + i] & 127], 1);
    __syncthreads();
    if (t < 128) {
        int n = (b << 7) + t;
        if (n < NN) degi[n] = cnt128[t];
    }
}

// ------- fused edge + L0 message gather, bf16 combined rows [y|A] -------
__global__ __launch_bounds__(256) void k_fused_edge(const int* __restrict__ rowptr,
        const int* __restrict__ ecol, const float* __restrict__ eat,
        const unsigned short* __restrict__ yab, const int* __restrict__ degi,
        const float* __restrict__ Wne, float* __restrict__ nedm,
        float* __restrict__ xagg0) {
    int t = threadIdx.x, wid = t >> 6, lane = t & 63;
    int n = blockIdx.x * 4 + wid;            // exact: NN/4
    float w0 = (lane < 63) ? Wne[lane] : 0.f;
    int s0 = rowptr[n], s1 = rowptr[n + 1];
    float accn = 0.f, accx = 0.f;
    for (int base = s0; base < s1; base += 64) {
        int m = min(64, s1 - base);
        int cc = (lane < m) ? ecol[base + lane] : 0;
        float aa = (lane < m) ? eat[base + lane] : 0.f;
        int j = 0;
        for (; j + 4 <= m; j += 4) {
            int c0 = __shfl(cc, j), c1 = __shfl(cc, j + 1);
            int c2 = __shfl(cc, j + 2), c3 = __shfl(cc, j + 3);
            float a0 = __shfl(aa, j), a1 = __shfl(aa, j + 1);
            float a2 = __shfl(aa, j + 2), a3 = __shfl(aa, j + 3);
            unsigned short y0 = yab[(size_t)c0 * 128 + lane], y1 = yab[(size_t)c1 * 128 + lane];
            unsigned short y2 = yab[(size_t)c2 * 128 + lane], y3 = yab[(size_t)c3 * 128 + lane];
            unsigned short v0 = yab[(size_t)c0 * 128 + 64 + lane], v1 = yab[(size_t)c1 * 128 + 64 + lane];
            unsigned short v2 = yab[(size_t)c2 * 128 + 64 + lane], v3 = yab[(size_t)c3 * 128 + 64 + lane];
            accn += fmaxf(fmaf(a0, w0, bf2f(y0)), 0.f);
            accn += fmaxf(fmaf(a1, w0, bf2f(y1)), 0.f);
            accn += fmaxf(fmaf(a2, w0, bf2f(y2)), 0.f);
            accn += fmaxf(fmaf(a3, w0, bf2f(y3)), 0.f);
            accx = fmaf(a0, bf2f(v0), accx); accx = fmaf(a1, bf2f(v1), accx);
            accx = fmaf(a2, bf2f(v2), accx); accx = fmaf(a3, bf2f(v3), accx);
        }
        for (; j < m; ++j) {
            int c = __shfl(cc, j);
            float a = __shfl(aa, j);
            accn += fmaxf(fmaf(a, w0, bf2f(yab[(size_t)c * 128 + lane])), 0.f);
            accx = fmaf(a, bf2f(yab[(size_t)c * 128 + 64 + lane]), accx);
        }
    }
    float inv = 1.f / fmaxf((float)(s1 - s0), 1.f);
    nedm[(size_t)n * DD + lane] = (lane < 63) ? accn * inv : (float)degi[n];
    xagg0[(size_t)n * DD + lane] = accx * inv;
}

// ------- fallback (fp32): edge gather only -------
__global__ __launch_bounds__(256) void k_edge_gather(const int* __restrict__ rowptr,
        const int* __restrict__ ecol, const float* __restrict__ eat,
        const float* __restrict__ y, const int* __restrict__ degi,
        const float* __restrict__ Wne, float* __restrict__ nedm) {
    int t = threadIdx.x, wid = t >> 6, lane = t & 63;
    int n = blockIdx.x * 4 + wid;
    float w0 = (lane < 63) ? Wne[lane] : 0.f;
    int s0 = rowptr[n], s1 = rowptr[n + 1];
    float acc = 0.f;
    for (int base = s0; base < s1; base += 64) {
        int m = min(64, s1 - base);
        int cc = (lane < m) ? ecol[base + lane] : 0;
        float aa = (lane < m) ? eat[base + lane] : 0.f;
        for (int j = 0; j < m; ++j) {
            int c = __shfl(cc, j);
            float a = __shfl(aa, j);
            acc += fmaxf(fmaf(a, w0, y[(size_t)c * DD + lane]), 0.f);
        }
    }
    float mean = acc / fmaxf((float)(s1 - s0), 1.f);
    nedm[(size_t)n * DD + lane] = (lane < 63) ? mean : (float)degi[n];
}

// ------- register-blocked GEMM: out = relu(in @ W), K=64; 32 nodes/block -------
__global__ __launch_bounds__(256) void k_gemm64(const float* __restrict__ in,
        const float* __restrict__ W, float* __restrict__ out) {
    __shared__ float sW[DD * DD];
    __shared__ float sI[32][DD];
    int t = threadIdx.x, wid = t >> 6, lane = t & 63;
    int nb = blockIdx.x * 32;        // exact: NN/32 = 3125
    for (int i = t; i < DD * DD / 4; i += 256)
        ((float4*)sW)[i] = ((const float4*)W)[i];
    for (int i = t; i < 32 * DD / 4; i += 256)
        ((float4*)sI)[i] = ((const float4*)(in + (size_t)nb * DD))[i];
    __syncthreads();
    float acc[8] = {0, 0, 0, 0, 0, 0, 0, 0};
    int n0 = wid * 8;
#pragma unroll 4
    for (int kc = 0; kc < 16; ++kc) {
        float w0 = sW[(4 * kc + 0) * DD + lane], w1 = sW[(4 * kc + 1) * DD + lane];
        float w2 = sW[(4 * kc + 2) * DD + lane], w3 = sW[(4 * kc + 3) * DD + lane];
#pragma unroll
        for (int j = 0; j < 8; ++j) {
            float4 v = *(const float4*)&sI[n0 + j][4 * kc];
            acc[j] = fmaf(v.x, w0, acc[j]); acc[j] = fmaf(v.y, w1, acc[j]);
            acc[j] = fmaf(v.z, w2, acc[j]); acc[j] = fmaf(v.w, w3, acc[j]);
        }
    }
#pragma unroll
    for (int j = 0; j < 8; ++j)
        out[(size_t)(nb + n0 + j) * DD + lane] = fmaxf(acc[j], 0.f);
}

// ------- fallback fp32 gather -------
__global__ __launch_bounds__(256) void k_gather32(const int* __restrict__ rowptr,
        const int* __restrict__ ecol, const float* __restrict__ eat,
        const float* __restrict__ xsrc, float* __restrict__ xagg) {
    int t = threadIdx.x, wid = t >> 6, lane = t & 63;
    int n = blockIdx.x * 4 + wid;
    int s0 = rowptr[n], s1 = rowptr[n + 1];
    float acc = 0.f;
    for (int base = s0; base < s1; base += 64) {
        int m = min(64, s1 - base);
        int cc = (lane < m) ? ecol[base + lane] : 0;
        float aa = (lane < m) ? eat[base + lane] : 0.f;
        for (int j = 0; j < m; ++j) {
            int c = __shfl(cc, j);
            float a = __shfl(aa, j);
            acc = fmaf(a, xsrc[(size_t)c * DD + lane], acc);
        }
    }
    xagg[(size_t)n * DD + lane] = acc / fmaxf((float)(s1 - s0), 1.f);
}

// ------- node update (staged xagg), 4x4 register tile; optional bf16 mirror -------
__global__ __launch_bounds__(256) void k_update(const float* __restrict__ xagg,
        const float* __restrict__ C, const float* __restrict__ xsrc,
        const float* __restrict__ Wm, const float* __restrict__ Wu,
        float* __restrict__ xdst, unsigned short* __restrict__ mir) {
    __shared__ __align__(16) float sX[64 * 68];
    __shared__ __align__(16) float sW[64 * 64];
    f32x4* sX4 = (f32x4*)sX;
    f32x4* sW4 = (f32x4*)sW;
    int t = threadIdx.x, tx = t & 15, ty = t >> 4;
    int nb = blockIdx.x * 64;                     // grid NNP/64 = 1563

    auto stageX = [&](const float* __restrict__ src) {
        const f32x4* g = (const f32x4*)src;
        for (int i = t; i < 1024; i += 256) {
            int r = i >> 4, c = i & 15;
            sX4[r * 17 + c] = g[(size_t)(nb + r) * 16 + c];
        }
    };
    auto stageW = [&](const float* __restrict__ w) {
        const f32x4* g = (const f32x4*)w;
        for (int i = t; i < 1024; i += 256) sW4[i] = g[i];
    };
    auto compute = [&](f32x4* acc) {
        const f32x4* x0 = sX4 + (4 * ty + 0) * 17;
        const f32x4* x1 = sX4 + (4 * ty + 1) * 17;
        const f32x4* x2 = sX4 + (4 * ty + 2) * 17;
        const f32x4* x3 = sX4 + (4 * ty + 3) * 17;
#pragma unroll 4
        for (int kc = 0; kc < 16; ++kc) {
            f32x4 a0 = x0[kc], a1 = x1[kc], a2 = x2[kc], a3 = x3[kc];
            f32x4 w0 = sW4[(4 * kc + 0) * 16 + tx];
            f32x4 w1 = sW4[(4 * kc + 1) * 16 + tx];
            f32x4 w2 = sW4[(4 * kc + 2) * 16 + tx];
            f32x4 w3 = sW4[(4 * kc + 3) * 16 + tx];
            acc[0] += a0[0] * w0; acc[0] += a0[1] * w1; acc[0] += a0[2] * w2; acc[0] += a0[3] * w3;
            acc[1] += a1[0] * w0; acc[1] += a1[1] * w1; acc[1] += a1[2] * w2; acc[1] += a1[3] * w3;
            acc[2] += a2[0] * w0; acc[2] += a2[1] * w1; acc[2] += a2[2] * w2; acc[2] += a2[3] * w3;
            acc[3] += a3[0] * w0; acc[3] += a3[1] * w1; acc[3] += a3[2] * w2; acc[3] += a3[3] * w3;
        }
    };

    f32x4 acc1[4] = {}, acc2[4] = {};
    stageX(xagg); stageW(Wm);
    __syncthreads(); compute(acc1); __syncthreads();
    stageX(C); stageW(Wm + 4096);
    __syncthreads(); compute(acc1); __syncthreads();
    f32x4 mm[4];
#pragma unroll
    for (int j = 0; j < 4; ++j) mm[j] = relu4(acc1[j]);
    stageX(xsrc); stageW(Wu);
    __syncthreads(); compute(acc2); __syncthreads();
#pragma unroll
    for (int j = 0; j < 4; ++j) sX4[(4 * ty + j) * 17 + tx] = mm[j];
    stageW(Wu + 4096);
    __syncthreads(); compute(acc2);
    f32x4* gout = (f32x4*)xdst;
#pragma unroll
    for (int j = 0; j < 4; ++j) {
        f32x4 r = relu4(acc2[j]);
        gout[(size_t)(nb + 4 * ty + j) * 16 + tx] = r;
        if (mir) {
            ushort4 mv;
            mv.x = f2bf(r[0]); mv.y = f2bf(r[1]); mv.z = f2bf(r[2]); mv.w = f2bf(r[3]);
            *(ushort4*)&mir[(size_t)(nb + 4 * ty + j) * DD + tx * 4] = mv;
        }
    }
}

// ------- FUSED gather+update: gather (bf16 msrc) -> sX in LDS, then both GEMMs -------
// Eliminates the xagg global round-trip. In/out row-disjoint: reads msrc cross-block
// (not written here), xsrc/C own rows; writes xdst + mir own rows.
__global__ __launch_bounds__(256) void k_fused_update(const int* __restrict__ rowptr,
        const int* __restrict__ ecol, const float* __restrict__ eat,
        const unsigned short* __restrict__ msrc, const float* __restrict__ C,
        const float* __restrict__ xsrc, const float* __restrict__ Wm,
        const float* __restrict__ Wu, float* __restrict__ xdst,
        unsigned short* __restrict__ mir) {
    __shared__ __align__(16) float sX[64 * 68];
    __shared__ __align__(16) float sW[64 * 64];
    f32x4* sX4 = (f32x4*)sX;
    f32x4* sW4 = (f32x4*)sW;
    int t = threadIdx.x, tx = t & 15, ty = t >> 4;
    int wid = t >> 6, lane = t & 63;
    int nb = blockIdx.x * 64;                     // grid NNP/64 = 1563

    // ---- phase 0: wave-per-node gather of 16 rows/wave into sX ----
    for (int i = 0; i < 16; ++i) {
        int r = (wid << 4) + i;
        int n = nb + r;
        float acc = 0.f;
        if (n < NN) {
            int s0 = rowptr[n], s1 = rowptr[n + 1];
            for (int base = s0; base < s1; base += 64) {
                int m = min(64, s1 - base);
                int cc = (lane < m) ? ecol[base + lane] : 0;
                float aa = (lane < m) ? eat[base + lane] : 0.f;
                int j = 0;
                for (; j + 8 <= m; j += 8) {
                    int c[8]; float a[8]; unsigned short v[8];
#pragma unroll
                    for (int u = 0; u < 8; ++u) { c[u] = __shfl(cc, j + u); a[u] = __shfl(aa, j + u); }
#pragma unroll
                    for (int u = 0; u < 8; ++u) v[u] = msrc[(size_t)c[u] * DD + lane];
#pragma unroll
                    for (int u = 0; u < 8; ++u) acc = fmaf(a[u], bf2f(v[u]), acc);
                }
                for (; j < m; ++j) {
                    int c = __shfl(cc, j);
                    float a = __shfl(aa, j);
                    acc = fmaf(a, bf2f(msrc[(size_t)c * DD + lane]), acc);
                }
            }
            acc /= fmaxf((float)(s1 - s0), 1.f);
        }
        sX[r * 68 + lane] = acc;
    }

    auto stageX = [&](const float* __restrict__ src) {
        const f32x4* g = (const f32x4*)src;
        for (int i = t; i < 1024; i += 256) {
            int r = i >> 4, c = i & 15;
            sX4[r * 17 + c] = g[(size_t)(nb + r) * 16 + c];
        }
    };
    auto stageW = [&](const float* __restrict__ w) {
        const f32x4* g = (const f32x4*)w;
        for (int i = t; i < 1024; i += 256) sW4[i] = g[i];
    };
    auto compute = [&](f32x4* acc) {
        const f32x4* x0 = sX4 + (4 * ty + 0) * 17;
        const f32x4* x1 = sX4 + (4 * ty + 1) * 17;
        const f32x4* x2 = sX4 + (4 * ty + 2) * 17;
        const f32x4* x3 = sX4 + (4 * ty + 3) * 17;
#pragma unroll 4
        for (int kc = 0; kc < 16; ++kc) {
            f32x4 a0 = x0[kc], a1 = x1[kc], a2 = x2[kc], a3 = x3[kc];
            f32x4 w0 = sW4[(4 * kc + 0) * 16 + tx];
            f32x4 w1 = sW4[(4 * kc + 1) * 16 + tx];
            f32x4 w2 = sW4[(4 * kc + 2) * 16 + tx];
            f32x4 w3 = sW4[(4 * kc + 3) * 16 + tx];
            acc[0] += a0[0] * w0; acc[0] += a0[1] * w1; acc[0] += a0[2] * w2; acc[0] += a0[3] * w3;
            acc[1] += a1[0] * w0; acc[1] += a1[1] * w1; acc[1] += a1[2] * w2; acc[1] += a1[3] * w3;
            acc[2] += a2[0] * w0; acc[2] += a2[1] * w1; acc[2] += a2[2] * w2; acc[2] += a2[3] * w3;
            acc[3] += a3[0] * w0; acc[3] += a3[1] * w1; acc[3] += a3[2] * w2; acc[3] += a3[3] * w3;
        }
    };

    f32x4 acc1[4] = {}, acc2[4] = {};
    stageW(Wm);                       // sX already holds gathered xagg
    __syncthreads(); compute(acc1); __syncthreads();
    stageX(C); stageW(Wm + 4096);
    __syncthreads(); compute(acc1); __syncthreads();
    f32x4 mm[4];
#pragma unroll
    for (int j = 0; j < 4; ++j) mm[j] = relu4(acc1[j]);
    stageX(xsrc); stageW(Wu);
    __syncthreads(); compute(acc2); __syncthreads();
#pragma unroll
    for (int j = 0; j < 4; ++j) sX4[(4 * ty + j) * 17 + tx] = mm[j];
    stageW(Wu + 4096);
    __syncthreads(); compute(acc2);
    f32x4* gout = (f32x4*)xdst;
#pragma unroll
    for (int j = 0; j < 4; ++j) {
        f32x4 r = relu4(acc2[j]);
        gout[(size_t)(nb + 4 * ty + j) * 16 + tx] = r;
        if (mir) {
            ushort4 mv;
            mv.x = f2bf(r[0]); mv.y = f2bf(r[1]); mv.z = f2bf(r[2]); mv.w = f2bf(r[3]);
            *(ushort4*)&mir[(size_t)(nb + 4 * ty + j) * DD + tx * 4] = mv;
        }
    }
}

// ---------- graph pool / graph GEMM / readout ----------
__global__ __launch_bounds__(256) void k_pool(const float* __restrict__ x_emb,
        const int* __restrict__ batch, float* __restrict__ g_sum,
        float* __restrict__ g_cnt) {
    int gid = blockIdx.x * 256 + threadIdx.x;
    int chunk = gid >> 6, d = gid & 63;
    if (chunk >= NCHUNK) return;
    int n0 = chunk * PCH;
    int curb = batch[n0];
    float s = 0.f, c = 0.f;
    for (int n = n0; n < n0 + PCH; ++n) {
        int b = batch[n];
        if (b != curb) {
            atomicAdd(&g_sum[curb * DD + d], s);
            if (d == 0) atomicAdd(&g_cnt[curb], c);
            s = 0.f; c = 0.f; curb = b;
        }
        s += x_emb[(size_t)n * DD + d];
        c += 1.f;
    }
    atomicAdd(&g_sum[curb * DD + d], s);
    if (d == 0) atomicAdd(&g_cnt[curb], c);
}

__global__ __launch_bounds__(256) void k_graph(const float* __restrict__ g_sum,
        const float* __restrict__ g_cnt, const float* __restrict__ Wg,
        float* __restrict__ g) {
    int gid = blockIdx.x * 256 + threadIdx.x;  // exact: 16 blocks
    int gi = gid >> 6, d = gid & 63;
    float c = fmaxf(g_cnt[gi], 1.f);
    float o = 0.f;
#pragma unroll 8
    for (int k = 0; k < DD; ++k) o += (g_sum[gi * DD + k] / c) * Wg[k * DD + d];
    g[gid] = fmaxf(o, 0.f);
}

__global__ __launch_bounds__(256) void k_readout(const float* __restrict__ x_emb,
        const float* __restrict__ g, const int* __restrict__ batch,
        const float* __restrict__ Wr, const float* __restrict__ br,
        float* __restrict__ q) {
    __shared__ float sWr[2 * DD];
    int t = threadIdx.x;
    if (t < 2 * DD) sWr[t] = Wr[t];
    __syncthreads();
    int n = blockIdx.x * 256 + t;
    if (n >= NN) return;
    int b = batch[n];
    const float* gr = g + b * DD;
    const float* xr = x_emb + (size_t)n * DD;
    float o = br[0];
#pragma unroll 8
    for (int k = 0; k < DD; ++k) o += gr[k] * sWr[k];
#pragma unroll 8
    for (int k = 0; k < DD; ++k) o += xr[k] * sWr[DD + k];
    q[n] = o;
}

extern "C" void kernel_launch(void* const* d_in, const int* in_sizes, int n_in,
                              void* d_out, int out_size, void* d_ws, size_t ws_size,
                              hipStream_t stream) {
    const float* x   = (const float*)d_in[0];
    const int*   ei  = (const int*)d_in[1];
    const float* ea  = (const float*)d_in[2];
    const int*   bat = (const int*)d_in[3];
    const float* Wn  = (const float*)d_in[4];
    const float* Wne = (const float*)d_in[5];
    const float* Wa  = (const float*)d_in[6];
    const float* Wm  = (const float*)d_in[7];
    const float* Wu  = (const float*)d_in[8];
    const float* Wg  = (const float*)d_in[9];
    const float* Wr  = (const float*)d_in[10];
    const float* br  = (const float*)d_in[11];
    float* q = (float*)d_out;

    const size_t FB = (size_t)NNP * DD;
    size_t need4 = (4 * FB + NE + 2 * (size_t)NG * DD + NG) * 4
                 + ((size_t)2 * NN + 1 + NE + 3 * RB + 64) * 4;
    bool fused = ws_size >= need4;

    float* A = (float*)d_ws;                     // x_emb ping (fp32)
    float* B = A + FB;                           // pong
    float* C = B + FB;                           // nedm -> x_agg_emb
    float* cur = C + FB;
    unsigned short* YAbf = fused ? (unsigned short*)cur : nullptr;
    unsigned short* Mb = YAbf;                   // mirror of L0 out
    unsigned short* Ma = YAbf ? YAbf + (size_t)NNP * DD : nullptr;  // mirror of L1 out
    float* Yf = fused ? nullptr : B;
    if (fused) cur += FB;
    float* eat   = cur;                          // NE
    float* g_sum = eat + NE;                     // NG*DD
    float* g_cnt = g_sum + NG * DD;              // NG
    float* g     = g_cnt + NG;                   // NG*DD
    int* degi    = (int*)(g + NG * DD);          // NN
    int* rowptr  = degi + NN;                    // NN+1
    int* ecol    = rowptr + NN + 1;              // NE
    int* gR      = ecol + NE;                    // RB
    int* gC      = gR + RB;                      // RB
    int* bsR     = gC + RB;                      // RB

    uint4* tmpR = (uint4*)A;                          // 25.6 MB (aliases A+B, dead)
    int*   tmpC = (int*)((char*)A + (size_t)RB * BCAP * 16);  // 6.4 MB

    hipMemsetAsync(gR, 0, (size_t)2 * RB * sizeof(int), stream);
    hipMemsetAsync(g_sum, 0, (size_t)(NG * DD + NG) * sizeof(float), stream);

    k_bucket<<<B1, 1024, 0, stream>>>(ei, ea, gR, gC, tmpR, tmpC);
    k_bscan<<<1, 1024, 0, stream>>>(gR, bsR);
    k_sortbucket<<<RB, 256, 0, stream>>>(gR, bsR, tmpR, rowptr, ecol, eat);
    k_degbucket<<<RB, 256, 0, stream>>>(gC, tmpC, degi);

    k_embed_xy<<<NN * DD / 256, 256, 0, stream>>>(x, Wn, Wne, A, YAbf, Yf);

    const int UB = NNP / 64;                     // 1563
    if (fused) {
        // one CSR pass over [y|A] bf16: nedm -> C, L0 xagg -> B
        k_fused_edge<<<NN / 4, 256, 0, stream>>>(rowptr, ecol, eat, YAbf, degi, Wne, C, B);
        k_gemm64<<<NN / 32, 256, 0, stream>>>(C, Wa, C);
        // L0 (staged xagg=B): xsrc=A -> B, mirror Mb (overwrites dead y-half region)
        k_update<<<UB, 256, 0, stream>>>(B, C, A, Wm, Wu, B, Mb);
        // L1 fused: gather Mb -> GEMMs; xsrc=B -> A, mirror Ma
        k_fused_update<<<UB, 256, 0, stream>>>(rowptr, ecol, eat, Mb, C, B,
            Wm + 8192, Wu + 8192, A, Ma);
        // L2 fused: gather Ma; xsrc=A -> B
        k_fused_update<<<UB, 256, 0, stream>>>(rowptr, ecol, eat, Ma, C, A,
            Wm + 16384, Wu + 16384, B, nullptr);
    } else {
        k_edge_gather<<<NN / 4, 256, 0, stream>>>(rowptr, ecol, eat, Yf, degi, Wne, C);
        k_gemm64<<<NN / 32, 256, 0, stream>>>(C, Wa, C);
        k_gather32<<<NN / 4, 256, 0, stream>>>(rowptr, ecol, eat, A, B);
        k_update<<<UB, 256, 0, stream>>>(B, C, A, Wm, Wu, B, nullptr);
        k_gather32<<<NN / 4, 256, 0, stream>>>(rowptr, ecol, eat, B, A);
        k_update<<<UB, 256, 0, stream>>>(A, C, B, Wm + 8192, Wu + 8192, A, nullptr);
        k_gather32<<<NN / 4, 256, 0, stream>>>(rowptr, ecol, eat, A, B);
        k_update<<<UB, 256, 0, stream>>>(B, C, A, Wm + 16384, Wu + 16384, B, nullptr);
    }

    k_pool<<<(NCHUNK * DD + 255) / 256, 256, 0, stream>>>(B, bat, g_sum, g_cnt);
    k_graph<<<NG * DD / 256, 256, 0, stream>>>(g_sum, g_cnt, Wg, g);
    k_readout<<<(NN + 255) / 256, 256, 0, stream>>>(B, g, bat, Wr, br, q);
}

// Round 8
// 503.864 us; speedup vs baseline: 1.2107x; 1.2107x over previous
//
#include <hip/hip_runtime.h>

#define NN 100000
#define NNP 100032          // padded to 64-node tiles
#define NE 1200000
#define DIN 7
#define DD 64
#define NL 3
#define NG 64
#define PCH 16
#define NCHUNK (NN / PCH)   // 6250
#define RB 782              // row/col buckets: 99999>>7 = 781
#define BCAP 2048           // per-bucket capacity (mean 1535, std ~39)
#define B1 250              // pass-1 blocks (1024 threads each)
#define CHUNK (NE / B1)     // 4800 exact

typedef float f32x4 __attribute__((ext_vector_type(4)));

__device__ inline f32x4 relu4(f32x4 v) {
    v[0] = fmaxf(v[0], 0.f); v[1] = fmaxf(v[1], 0.f);
    v[2] = fmaxf(v[2], 0.f); v[3] = fmaxf(v[3], 0.f);
    return v;
}
__device__ inline unsigned short f2bf(float f) {        // RNE bf16
    unsigned u = __float_as_uint(f);
    return (unsigned short)((u + 0x7fffu + ((u >> 16) & 1u)) >> 16);
}
__device__ inline float bf2f(unsigned short h) {
    return __uint_as_float(((unsigned)h) << 16);
}

// ------------- fused embed: A = relu(x@Wn) fp32; YAbf[n] = [y bf16 (64) | A bf16 (64)] -------------
__global__ __launch_bounds__(256) void k_embed_xy(const float* __restrict__ x,
        const float* __restrict__ Wn, const float* __restrict__ Wne,
        float* __restrict__ A, unsigned short* __restrict__ yab,
        float* __restrict__ yf) {
    __shared__ float sWn[DIN * DD];
    __shared__ float sWy[DIN * DD];
    int t = threadIdx.x;
    for (int i = t; i < DIN * DD; i += 256) {
        sWn[i] = Wn[i];
        int k = i >> 6, d = i & 63;
        sWy[i] = (d < 63) ? Wne[(k + 1) * 63 + d] : 0.f;
    }
    __syncthreads();
    int gid = blockIdx.x * 256 + t;          // exact grid: NN*DD/256
    int n = gid >> 6, d = gid & 63;
    const float* xr = x + n * DIN;
    float a = 0.f, y = 0.f;
#pragma unroll
    for (int k = 0; k < DIN; ++k) {
        float xv = xr[k];
        a = fmaf(xv, sWn[k * DD + d], a);
        y = fmaf(xv, sWy[k * DD + d], y);
    }
    float ar = fmaxf(a, 0.f);
    A[gid] = ar;
    if (yab) {
        yab[(size_t)n * 128 + d] = f2bf(y);
        yab[(size_t)n * 128 + 64 + d] = f2bf(ar);
    }
    if (yf) yf[gid] = y;
}

// ---------------- CSR build via LDS bucket sort ----------------
__global__ __launch_bounds__(1024) void k_bucket(const int* __restrict__ ei,
        const float* __restrict__ ea, int* __restrict__ gR, int* __restrict__ gC,
        uint4* __restrict__ tmpR, int* __restrict__ tmpC) {
    __shared__ int hR[RB], hC[RB];
    int t = threadIdx.x;
    for (int i = t; i < RB; i += 1024) { hR[i] = 0; hC[i] = 0; }
    __syncthreads();
    int e0 = blockIdx.x * CHUNK, e1 = e0 + CHUNK;
    for (int e = e0 + t; e < e1; e += 1024) {
        atomicAdd(&hR[ei[e] >> 7], 1);
        atomicAdd(&hC[ei[NE + e] >> 7], 1);
    }
    __syncthreads();
    for (int b = t; b < RB; b += 1024) {
        int n = hR[b]; hR[b] = n ? atomicAdd(&gR[b], n) : 0;
        n = hC[b];     hC[b] = n ? atomicAdd(&gC[b], n) : 0;
    }
    __syncthreads();
    for (int e = e0 + t; e < e1; e += 1024) {
        int r = ei[e], c = ei[NE + e];
        float a = ea[e];
        int br = r >> 7, bc = c >> 7;
        int ir = atomicAdd(&hR[br], 1);
        if (ir < BCAP) tmpR[(size_t)br * BCAP + ir] = make_uint4((unsigned)r, (unsigned)c, __float_as_uint(a), 0u);
        int ic = atomicAdd(&hC[bc], 1);
        if (ic < BCAP) tmpC[(size_t)bc * BCAP + ic] = c;
    }
}

__global__ __launch_bounds__(1024) void k_bscan(const int* __restrict__ gR,
        int* __restrict__ bsR) {
    __shared__ int s[1024];
    int t = threadIdx.x;
    int v = (t < RB) ? gR[t] : 0;
    s[t] = v; __syncthreads();
    for (int off = 1; off < 1024; off <<= 1) {
        int u = (t >= off) ? s[t - off] : 0; __syncthreads();
        s[t] += u; __syncthreads();
    }
    if (t < RB) bsR[t] = s[t] - v;
}

__global__ __launch_bounds__(256) void k_sortbucket(const int* __restrict__ gR,
        const int* __restrict__ bsR, const uint4* __restrict__ tmpR,
        int* __restrict__ rowptr, int* __restrict__ ecol, float* __restrict__ eat) {
    __shared__ uint4 sbuf[BCAP];              // 32 KB
    __shared__ int cnt128[128], off128[128], sscan[128];
    int b = blockIdx.x, t = threadIdx.x;
    int cnt = min(gR[b], BCAP);
    int base = bsR[b];
    if (t < 128) cnt128[t] = 0;
    __syncthreads();
    for (int i = t; i < cnt; i += 256) {
        uint4 rec = tmpR[(size_t)b * BCAP + i];
        sbuf[i] = rec;
        atomicAdd(&cnt128[rec.x & 127], 1);
    }
    __syncthreads();
    if (t < 128) sscan[t] = cnt128[t];
    __syncthreads();
    for (int off = 1; off < 128; off <<= 1) {
        int u = (t < 128 && t >= off) ? sscan[t - off] : 0;
        __syncthreads();
        if (t < 128) sscan[t] += u;
        __syncthreads();
    }
    if (t < 128) {
        int excl = sscan[t] - cnt128[t];
        off128[t] = excl;
        int row = (b << 7) + t;
        if (row <= NN) rowptr[row] = base + excl;
    }
    __syncthreads();
    for (int i = t; i < cnt; i += 256) {
        uint4 rec = sbuf[i];
        int p = atomicAdd(&off128[rec.x & 127], 1);
        ecol[base + p] = (int)rec.y;
        eat[base + p] = __uint_as_float(rec.z);
    }
}

__global__ __launch_bounds__(256) void k_degbucket(const int* __restrict__ gC,
        const int* __restrict__ tmpC, int* __restrict__ degi) {
    __shared__ int cnt128[128];
    int b = blockIdx.x, t = threadIdx.x;
    int cnt = min(gC[b], BCAP);
    if (t < 128) cnt128[t] = 0;
    __syncthreads();
    for (int i = t; i < cnt; i += 256)
        atomicAdd(&cnt128[tmpC[(size_t)b * BCAP + i] & 127], 1);
    __syncthreads();
    if (t < 128) {
        int n = (b << 7) + t;
        if (n < NN) degi[n] = cnt128[t];
    }
}

// ------- fused edge + L0 message gather, bf16 combined rows [y|A] -------
__global__ __launch_bounds__(256) void k_fused_edge(const int* __restrict__ rowptr,
        const int* __restrict__ ecol, const float* __restrict__ eat,
        const unsigned short* __restrict__ yab, const int* __restrict__ degi,
        const float* __restrict__ Wne, float* __restrict__ nedm,
        float* __restrict__ xagg0) {
    int t = threadIdx.x, wid = t >> 6, lane = t & 63;
    int n = blockIdx.x * 4 + wid;            // exact: NN/4
    float w0 = (lane < 63) ? Wne[lane] : 0.f;
    int s0 = rowptr[n], s1 = rowptr[n + 1];
    float accn = 0.f, accx = 0.f;
    for (int base = s0; base < s1; base += 64) {
        int m = min(64, s1 - base);
        int cc = (lane < m) ? ecol[base + lane] : 0;
        float aa = (lane < m) ? eat[base + lane] : 0.f;
        int j = 0;
        for (; j + 4 <= m; j += 4) {
            int c0 = __shfl(cc, j), c1 = __shfl(cc, j + 1);
            int c2 = __shfl(cc, j + 2), c3 = __shfl(cc, j + 3);
            float a0 = __shfl(aa, j), a1 = __shfl(aa, j + 1);
            float a2 = __shfl(aa, j + 2), a3 = __shfl(aa, j + 3);
            unsigned short y0 = yab[(size_t)c0 * 128 + lane], y1 = yab[(size_t)c1 * 128 + lane];
            unsigned short y2 = yab[(size_t)c2 * 128 + lane], y3 = yab[(size_t)c3 * 128 + lane];
            unsigned short v0 = yab[(size_t)c0 * 128 + 64 + lane], v1 = yab[(size_t)c1 * 128 + 64 + lane];
            unsigned short v2 = yab[(size_t)c2 * 128 + 64 + lane], v3 = yab[(size_t)c3 * 128 + 64 + lane];
            accn += fmaxf(fmaf(a0, w0, bf2f(y0)), 0.f);
            accn += fmaxf(fmaf(a1, w0, bf2f(y1)), 0.f);
            accn += fmaxf(fmaf(a2, w0, bf2f(y2)), 0.f);
            accn += fmaxf(fmaf(a3, w0, bf2f(y3)), 0.f);
            accx = fmaf(a0, bf2f(v0), accx); accx = fmaf(a1, bf2f(v1), accx);
            accx = fmaf(a2, bf2f(v2), accx); accx = fmaf(a3, bf2f(v3), accx);
        }
        for (; j < m; ++j) {
            int c = __shfl(cc, j);
            float a = __shfl(aa, j);
            accn += fmaxf(fmaf(a, w0, bf2f(yab[(size_t)c * 128 + lane])), 0.f);
            accx = fmaf(a, bf2f(yab[(size_t)c * 128 + 64 + lane]), accx);
        }
    }
    float inv = 1.f / fmaxf((float)(s1 - s0), 1.f);
    nedm[(size_t)n * DD + lane] = (lane < 63) ? accn * inv : (float)degi[n];
    xagg0[(size_t)n * DD + lane] = accx * inv;
}

// ------- fallback (fp32): edge gather only -------
__global__ __launch_bounds__(256) void k_edge_gather(const int* __restrict__ rowptr,
        const int* __restrict__ ecol, const float* __restrict__ eat,
        const float* __restrict__ y, const int* __restrict__ degi,
        const float* __restrict__ Wne, float* __restrict__ nedm) {
    int t = threadIdx.x, wid = t >> 6, lane = t & 63;
    int n = blockIdx.x * 4 + wid;
    float w0 = (lane < 63) ? Wne[lane] : 0.f;
    int s0 = rowptr[n], s1 = rowptr[n + 1];
    float acc = 0.f;
    for (int base = s0; base < s1; base += 64) {
        int m = min(64, s1 - base);
        int cc = (lane < m) ? ecol[base + lane] : 0;
        float aa = (lane < m) ? eat[base + lane] : 0.f;
        for (int j = 0; j < m; ++j) {
            int c = __shfl(cc, j);
            float a = __shfl(aa, j);
            acc += fmaxf(fmaf(a, w0, y[(size_t)c * DD + lane]), 0.f);
        }
    }
    float mean = acc / fmaxf((float)(s1 - s0), 1.f);
    nedm[(size_t)n * DD + lane] = (lane < 63) ? mean : (float)degi[n];
}

// ------- register-blocked GEMM: out = relu(in @ W), K=64; 32 nodes/block -------
__global__ __launch_bounds__(256) void k_gemm64(const float* __restrict__ in,
        const float* __restrict__ W, float* __restrict__ out) {
    __shared__ float sW[DD * DD];
    __shared__ float sI[32][DD];
    int t = threadIdx.x, wid = t >> 6, lane = t & 63;
    int nb = blockIdx.x * 32;        // exact: NN/32 = 3125
    for (int i = t; i < DD * DD / 4; i += 256)
        ((float4*)sW)[i] = ((const float4*)W)[i];
    for (int i = t; i < 32 * DD / 4; i += 256)
        ((float4*)sI)[i] = ((const float4*)(in + (size_t)nb * DD))[i];
    __syncthreads();
    float acc[8] = {0, 0, 0, 0, 0, 0, 0, 0};
    int n0 = wid * 8;
#pragma unroll 4
    for (int kc = 0; kc < 16; ++kc) {
        float w0 = sW[(4 * kc + 0) * DD + lane], w1 = sW[(4 * kc + 1) * DD + lane];
        float w2 = sW[(4 * kc + 2) * DD + lane], w3 = sW[(4 * kc + 3) * DD + lane];
#pragma unroll
        for (int j = 0; j < 8; ++j) {
            float4 v = *(const float4*)&sI[n0 + j][4 * kc];
            acc[j] = fmaf(v.x, w0, acc[j]); acc[j] = fmaf(v.y, w1, acc[j]);
            acc[j] = fmaf(v.z, w2, acc[j]); acc[j] = fmaf(v.w, w3, acc[j]);
        }
    }
#pragma unroll
    for (int j = 0; j < 8; ++j)
        out[(size_t)(nb + n0 + j) * DD + lane] = fmaxf(acc[j], 0.f);
}

// ------- message gather (bf16 src): xagg[n] = mean_e ea * xsrc[col] -------
__global__ __launch_bounds__(256) void k_gather(const int* __restrict__ rowptr,
        const int* __restrict__ ecol, const float* __restrict__ eat,
        const unsigned short* __restrict__ xsrc, float* __restrict__ xagg) {
    int t = threadIdx.x, wid = t >> 6, lane = t & 63;
    int n = blockIdx.x * 4 + wid;            // exact: NN/4
    int s0 = rowptr[n], s1 = rowptr[n + 1];
    float acc = 0.f;
    for (int base = s0; base < s1; base += 64) {
        int m = min(64, s1 - base);
        int cc = (lane < m) ? ecol[base + lane] : 0;
        float aa = (lane < m) ? eat[base + lane] : 0.f;
        int j = 0;
        for (; j + 8 <= m; j += 8) {
            int c[8]; float a[8]; unsigned short v[8];
#pragma unroll
            for (int u = 0; u < 8; ++u) { c[u] = __shfl(cc, j + u); a[u] = __shfl(aa, j + u); }
#pragma unroll
            for (int u = 0; u < 8; ++u) v[u] = xsrc[(size_t)c[u] * DD + lane];
#pragma unroll
            for (int u = 0; u < 8; ++u) acc = fmaf(a[u], bf2f(v[u]), acc);
        }
        for (; j < m; ++j) {
            int c = __shfl(cc, j);
            float a = __shfl(aa, j);
            acc = fmaf(a, bf2f(xsrc[(size_t)c * DD + lane]), acc);
        }
    }
    xagg[(size_t)n * DD + lane] = acc / fmaxf((float)(s1 - s0), 1.f);
}

// ------- fallback fp32 gather -------
__global__ __launch_bounds__(256) void k_gather32(const int* __restrict__ rowptr,
        const int* __restrict__ ecol, const float* __restrict__ eat,
        const float* __restrict__ xsrc, float* __restrict__ xagg) {
    int t = threadIdx.x, wid = t >> 6, lane = t & 63;
    int n = blockIdx.x * 4 + wid;
    int s0 = rowptr[n], s1 = rowptr[n + 1];
    float acc = 0.f;
    for (int base = s0; base < s1; base += 64) {
        int m = min(64, s1 - base);
        int cc = (lane < m) ? ecol[base + lane] : 0;
        float aa = (lane < m) ? eat[base + lane] : 0.f;
        for (int j = 0; j < m; ++j) {
            int c = __shfl(cc, j);
            float a = __shfl(aa, j);
            acc = fmaf(a, xsrc[(size_t)c * DD + lane], acc);
        }
    }
    xagg[(size_t)n * DD + lane] = acc / fmaxf((float)(s1 - s0), 1.f);
}

// ------- node update, FAT phases: one K=128 staging + full-W staging, 3 syncs -------
// m = relu([xagg,C]@Wm); xdst = relu([xsrc,m]@Wu). In-place safe (xagg==xdst ok).
__global__ __launch_bounds__(256) void k_update(const float* __restrict__ xagg,
        const float* __restrict__ C, const float* __restrict__ xsrc,
        const float* __restrict__ Wm, const float* __restrict__ Wu,
        float* __restrict__ xdst, unsigned short* __restrict__ mir) {
    __shared__ __align__(16) float sX[64 * 132];   // 64 rows x (128 + 4 pad) = 33792 B
    __shared__ __align__(16) float sW[128 * 64];   // full weight, 32768 B
    f32x4* sX4 = (f32x4*)sX;                       // row stride 33 f32x4
    f32x4* sW4 = (f32x4*)sW;
    int t = threadIdx.x, tx = t & 15, ty = t >> 4;
    int nb = blockIdx.x * 64;                      // grid NNP/64 = 1563

    // ---- phase 1: stage [xagg | C] (K=128) + full Wm; 16 loads/thread in flight ----
    {
        const f32x4* gx = (const f32x4*)xagg;
        const f32x4* gc = (const f32x4*)C;
        for (int i = t; i < 2048; i += 256) {
            int r = i >> 5, c = i & 31;
            f32x4 v = (c < 16) ? gx[(size_t)(nb + r) * 16 + c]
                               : gc[(size_t)(nb + r) * 16 + (c - 16)];
            sX4[r * 33 + c] = v;
        }
        const f32x4* gw = (const f32x4*)Wm;
        for (int i = t; i < 2048; i += 256) sW4[i] = gw[i];
    }
    __syncthreads();
    f32x4 acc1[4] = {};
    {
        const f32x4* xr = sX4 + (4 * ty) * 33;
#pragma unroll 4
        for (int kc = 0; kc < 32; ++kc) {
            f32x4 w0 = sW4[(4 * kc + 0) * 16 + tx];
            f32x4 w1 = sW4[(4 * kc + 1) * 16 + tx];
            f32x4 w2 = sW4[(4 * kc + 2) * 16 + tx];
            f32x4 w3 = sW4[(4 * kc + 3) * 16 + tx];
#pragma unroll
            for (int j = 0; j < 4; ++j) {
                f32x4 a = xr[j * 33 + kc];
                acc1[j] += a[0] * w0; acc1[j] += a[1] * w1;
                acc1[j] += a[2] * w2; acc1[j] += a[3] * w3;
            }
        }
    }
    __syncthreads();
    // ---- phase 2: stage [xsrc | m] + full Wu ----
    {
        const f32x4* gs = (const f32x4*)xsrc;
        for (int i = t; i < 1024; i += 256) {
            int r = i >> 4, c = i & 15;
            sX4[r * 33 + c] = gs[(size_t)(nb + r) * 16 + c];
        }
#pragma unroll
        for (int j = 0; j < 4; ++j)
            sX4[(4 * ty + j) * 33 + 16 + tx] = relu4(acc1[j]);
        const f32x4* gw = (const f32x4*)Wu;
        for (int i = t; i < 2048; i += 256) sW4[i] = gw[i];
    }
    __syncthreads();
    f32x4 acc2[4] = {};
    {
        const f32x4* xr = sX4 + (4 * ty) * 33;
#pragma unroll 4
        for (int kc = 0; kc < 32; ++kc) {
            f32x4 w0 = sW4[(4 * kc + 0) * 16 + tx];
            f32x4 w1 = sW4[(4 * kc + 1) * 16 + tx];
            f32x4 w2 = sW4[(4 * kc + 2) * 16 + tx];
            f32x4 w3 = sW4[(4 * kc + 3) * 16 + tx];
#pragma unroll
            for (int j = 0; j < 4; ++j) {
                f32x4 a = xr[j * 33 + kc];
                acc2[j] += a[0] * w0; acc2[j] += a[1] * w1;
                acc2[j] += a[2] * w2; acc2[j] += a[3] * w3;
            }
        }
    }
    f32x4* gout = (f32x4*)xdst;
#pragma unroll
    for (int j = 0; j < 4; ++j) {
        f32x4 r = relu4(acc2[j]);
        gout[(size_t)(nb + 4 * ty + j) * 16 + tx] = r;
        if (mir) {
            ushort4 mv;
            mv.x = f2bf(r[0]); mv.y = f2bf(r[1]); mv.z = f2bf(r[2]); mv.w = f2bf(r[3]);
            *(ushort4*)&mir[(size_t)(nb + 4 * ty + j) * DD + tx * 4] = mv;
        }
    }
}

// ---------- graph pool / graph GEMM / readout ----------
__global__ __launch_bounds__(256) void k_pool(const float* __restrict__ x_emb,
        const int* __restrict__ batch, float* __restrict__ g_sum,
        float* __restrict__ g_cnt) {
    int gid = blockIdx.x * 256 + threadIdx.x;
    int chunk = gid >> 6, d = gid & 63;
    if (chunk >= NCHUNK) return;
    int n0 = chunk * PCH;
    int curb = batch[n0];
    float s = 0.f, c = 0.f;
    for (int n = n0; n < n0 + PCH; ++n) {
        int b = batch[n];
        if (b != curb) {
            atomicAdd(&g_sum[curb * DD + d], s);
            if (d == 0) atomicAdd(&g_cnt[curb], c);
            s = 0.f; c = 0.f; curb = b;
        }
        s += x_emb[(size_t)n * DD + d];
        c += 1.f;
    }
    atomicAdd(&g_sum[curb * DD + d], s);
    if (d == 0) atomicAdd(&g_cnt[curb], c);
}

__global__ __launch_bounds__(256) void k_graph(const float* __restrict__ g_sum,
        const float* __restrict__ g_cnt, const float* __restrict__ Wg,
        float* __restrict__ g) {
    int gid = blockIdx.x * 256 + threadIdx.x;  // exact: 16 blocks
    int gi = gid >> 6, d = gid & 63;
    float c = fmaxf(g_cnt[gi], 1.f);
    float o = 0.f;
#pragma unroll 8
    for (int k = 0; k < DD; ++k) o += (g_sum[gi * DD + k] / c) * Wg[k * DD + d];
    g[gid] = fmaxf(o, 0.f);
}

__global__ __launch_bounds__(256) void k_readout(const float* __restrict__ x_emb,
        const float* __restrict__ g, const int* __restrict__ batch,
        const float* __restrict__ Wr, const float* __restrict__ br,
        float* __restrict__ q) {
    __shared__ float sWr[2 * DD];
    int t = threadIdx.x;
    if (t < 2 * DD) sWr[t] = Wr[t];
    __syncthreads();
    int n = blockIdx.x * 256 + t;
    if (n >= NN) return;
    int b = batch[n];
    const float* gr = g + b * DD;
    const float* xr = x_emb + (size_t)n * DD;
    float o = br[0];
#pragma unroll 8
    for (int k = 0; k < DD; ++k) o += gr[k] * sWr[k];
#pragma unroll 8
    for (int k = 0; k < DD; ++k) o += xr[k] * sWr[DD + k];
    q[n] = o;
}

extern "C" void kernel_launch(void* const* d_in, const int* in_sizes, int n_in,
                              void* d_out, int out_size, void* d_ws, size_t ws_size,
                              hipStream_t stream) {
    const float* x   = (const float*)d_in[0];
    const int*   ei  = (const int*)d_in[1];
    const float* ea  = (const float*)d_in[2];
    const int*   bat = (const int*)d_in[3];
    const float* Wn  = (const float*)d_in[4];
    const float* Wne = (const float*)d_in[5];
    const float* Wa  = (const float*)d_in[6];
    const float* Wm  = (const float*)d_in[7];
    const float* Wu  = (const float*)d_in[8];
    const float* Wg  = (const float*)d_in[9];
    const float* Wr  = (const float*)d_in[10];
    const float* br  = (const float*)d_in[11];
    float* q = (float*)d_out;

    const size_t FB = (size_t)NNP * DD;
    size_t need4 = (4 * FB + NE + 2 * (size_t)NG * DD + NG) * 4
                 + ((size_t)2 * NN + 1 + NE + 3 * RB + 64) * 4;
    bool fused = ws_size >= need4;

    float* A = (float*)d_ws;                     // x_emb ping (fp32)
    float* B = A + FB;                           // pong
    float* C = B + FB;                           // nedm -> x_agg_emb
    float* cur = C + FB;
    unsigned short* YAbf = fused ? (unsigned short*)cur : nullptr;
    unsigned short* Mb = YAbf;                   // mirror of L0 out
    unsigned short* Ma = YAbf ? YAbf + (size_t)NNP * DD : nullptr;  // mirror of L1 out
    float* Yf = fused ? nullptr : B;
    if (fused) cur += FB;
    float* eat   = cur;                          // NE
    float* g_sum = eat + NE;                     // NG*DD
    float* g_cnt = g_sum + NG * DD;              // NG
    float* g     = g_cnt + NG;                   // NG*DD
    int* degi    = (int*)(g + NG * DD);          // NN
    int* rowptr  = degi + NN;                    // NN+1
    int* ecol    = rowptr + NN + 1;              // NE
    int* gR      = ecol + NE;                    // RB
    int* gC      = gR + RB;                      // RB
    int* bsR     = gC + RB;                      // RB

    uint4* tmpR = (uint4*)A;                          // 25.6 MB (aliases A+B, dead)
    int*   tmpC = (int*)((char*)A + (size_t)RB * BCAP * 16);  // 6.4 MB

    hipMemsetAsync(gR, 0, (size_t)2 * RB * sizeof(int), stream);
    hipMemsetAsync(g_sum, 0, (size_t)(NG * DD + NG) * sizeof(float), stream);

    k_bucket<<<B1, 1024, 0, stream>>>(ei, ea, gR, gC, tmpR, tmpC);
    k_bscan<<<1, 1024, 0, stream>>>(gR, bsR);
    k_sortbucket<<<RB, 256, 0, stream>>>(gR, bsR, tmpR, rowptr, ecol, eat);
    k_degbucket<<<RB, 256, 0, stream>>>(gC, tmpC, degi);

    k_embed_xy<<<NN * DD / 256, 256, 0, stream>>>(x, Wn, Wne, A, YAbf, Yf);

    const int UB = NNP / 64;                     // 1563
    if (fused) {
        // one CSR pass over [y|A] bf16: nedm -> C, L0 xagg -> B
        k_fused_edge<<<NN / 4, 256, 0, stream>>>(rowptr, ecol, eat, YAbf, degi, Wne, C, B);
        k_gemm64<<<NN / 32, 256, 0, stream>>>(C, Wa, C);
        // L0: xagg=B, xsrc=A -> B, mirror Mb (overwrites dead y-half region)
        k_update<<<UB, 256, 0, stream>>>(B, C, A, Wm, Wu, B, Mb);
        // L1: gather Mb -> A; update xagg=A, xsrc=B -> A, mirror Ma
        k_gather<<<NN / 4, 256, 0, stream>>>(rowptr, ecol, eat, Mb, A);
        k_update<<<UB, 256, 0, stream>>>(A, C, B, Wm + 8192, Wu + 8192, A, Ma);
        // L2: gather Ma -> B; update xagg=B, xsrc=A -> B
        k_gather<<<NN / 4, 256, 0, stream>>>(rowptr, ecol, eat, Ma, B);
        k_update<<<UB, 256, 0, stream>>>(B, C, A, Wm + 16384, Wu + 16384, B, nullptr);
    } else {
        k_edge_gather<<<NN / 4, 256, 0, stream>>>(rowptr, ecol, eat, Yf, degi, Wne, C);
        k_gemm64<<<NN / 32, 256, 0, stream>>>(C, Wa, C);
        k_gather32<<<NN / 4, 256, 0, stream>>>(rowptr, ecol, eat, A, B);
        k_update<<<UB, 256, 0, stream>>>(B, C, A, Wm, Wu, B, nullptr);
        k_gather32<<<NN / 4, 256, 0, stream>>>(rowptr, ecol, eat, B, A);
        k_update<<<UB, 256, 0, stream>>>(A, C, B, Wm + 8192, Wu + 8192, A, nullptr);
        k_gather32<<<NN / 4, 256, 0, stream>>>(rowptr, ecol, eat, A, B);
        k_update<<<UB, 256, 0, stream>>>(B, C, A, Wm + 16384, Wu + 16384, B, nullptr);
    }

    k_pool<<<(NCHUNK * DD + 255) / 256, 256, 0, stream>>>(B, bat, g_sum, g_cnt);
    k_graph<<<NG * DD / 256, 256, 0, stream>>>(g_sum, g_cnt, Wg, g);
    k_readout<<<(NN + 255) / 256, 256, 0, stream>>>(B, g, bat, Wr, br, q);
}